// Round 7
// baseline (131.244 us; speedup 1.0000x reference)
//
#include <hip/hip_runtime.h>
#include <cmath>

#define B_N 8192
#define D_K 128
#define CSPLIT 8                 // column splits; block covers 1024 cols
#define T_ITERS 16               // 16-col tiles per wave: 1024 / 4 waves / 16
#define GRID_MPL (256 * CSPLIT)  // 2048 blocks

typedef float f32x4 __attribute__((ext_vector_type(4)));
typedef long  lx2   __attribute__((ext_vector_type(2)));

// Convert fp32 Q and A to fp8 e4m3 (OCP, RNE via v_cvt_pk_fp8_f32 — gfx950 emits
// OCP format), both stored MFMA-fragment-packed:
//   per 16-elem tile T (row-tile for Q, col-tile for A), per k-pair p in {0,1}:
//   1 KB region at (T*2+p)*1024; lane L (quad=L>>4, e=L&15) holds 16 B at L*16 =
//   X[T*16+e][k = (2p)*32 + quad*8 ..+7] ++ X[T*16+e][k = (2p+1)*32 + quad*8 ..+7].
// Main kernel loads operand frags as base + lane*16: 1 KB contiguous per b128
// (R4-verified TA win), and fp8 halves bytes vs bf16 (R5 diagnosis: L2-byte-bound).
// Also zeroes the done-counter (ws is re-poisoned 0xAA before every replay).
__global__ void cvt_kernel(const float* __restrict__ q, const float* __restrict__ a,
                           unsigned char* __restrict__ qp, unsigned char* __restrict__ ap,
                           unsigned int* __restrict__ cnt) {
    const int g = blockIdx.x * blockDim.x + threadIdx.x;   // 0 .. B*D/8-1
    if (g == 0) *cnt = 0u;

    float4 q0 = reinterpret_cast<const float4*>(q)[g * 2];
    float4 q1 = reinterpret_cast<const float4*>(q)[g * 2 + 1];
    float4 a0 = reinterpret_cast<const float4*>(a)[g * 2];
    float4 a1 = reinterpret_cast<const float4*>(a)[g * 2 + 1];

    int qw0 = __builtin_amdgcn_cvt_pk_fp8_f32(q0.x, q0.y, 0, false);
    qw0     = __builtin_amdgcn_cvt_pk_fp8_f32(q0.z, q0.w, qw0, true);
    int qw1 = __builtin_amdgcn_cvt_pk_fp8_f32(q1.x, q1.y, 0, false);
    qw1     = __builtin_amdgcn_cvt_pk_fp8_f32(q1.z, q1.w, qw1, true);
    int aw0 = __builtin_amdgcn_cvt_pk_fp8_f32(a0.x, a0.y, 0, false);
    aw0     = __builtin_amdgcn_cvt_pk_fp8_f32(a0.z, a0.w, aw0, true);
    int aw1 = __builtin_amdgcn_cvt_pk_fp8_f32(a1.x, a1.y, 0, false);
    aw1     = __builtin_amdgcn_cvt_pk_fp8_f32(a1.z, a1.w, aw1, true);

    const int idx  = g >> 4;          // row (Q) / col (A)
    const int sq   = g & 15;          // covers k = sq*8 .. +7
    const int s    = sq >> 2;         // k-step (32 k each)
    const int quad = sq & 3;
    const int tile = idx >> 4, e = idx & 15;
    const int lane = quad * 16 + e;
    const size_t off = ((size_t)(tile * 2 + (s >> 1)) << 10) + (size_t)lane * 16 + (size_t)(s & 1) * 8;
    *reinterpret_cast<int2*>(qp + off) = make_int2(qw0, qw1);
    *reinterpret_cast<int2*>(ap + off) = make_int2(aw0, aw1);
}

// Fused partial + last-block finalize. Block (rg, cs): rows [rg*32,+32) over cols
// [cs*1024,+1024). 256 threads = 4 waves; wave owns 256 cols (16 tiles of 16).
// MFMA 16x16x32 fp8_fp8 (same lane mapping as verified bf16 16x16x32; K=32, 8 B/lane):
//   A-op: lane holds A[m=lane&15][k=(lane>>4)*8+j]; B-op transposed same; C/D:
//   col=lane&15, row=(lane>>4)*4+reg.
// Accuracy via mxp (max over positive cols) == mxv (global max).
// Cross-block: partials stored agent-scope relaxed by wave 0; explicit release
// fence before the done-counter fetch_add; last block acquire-fences + finalizes.
__launch_bounds__(256, 4)
__global__ void mpl_kernel(const unsigned char* __restrict__ qp,
                           const unsigned char* __restrict__ ap,
                           const int* __restrict__ qids,
                           const float* __restrict__ ranks,
                           float* __restrict__ pden, float* __restrict__ pnum,
                           float* __restrict__ pmax, float* __restrict__ pmaxp,
                           unsigned int* __restrict__ cnt,
                           float* __restrict__ out) {
    const int tid  = threadIdx.x;
    const int lane = tid & 63;
    const int wave = tid >> 6;               // 0..3
    const int rg   = blockIdx.x >> 3;        // 0..255
    const int cs   = blockIdx.x & 7;         // 0..7 (== XCD id under %8 dispatch)
    const int rowBase = rg * 32;
    const int quad = lane >> 4;              // 0..3
    const int l15  = lane & 15;

    // Q fragments for K=128 (4 k-steps) x 2 row-tiles: 2 b128 loads per row-tile.
    long qfrag[2][4];
    #pragma unroll
    for (int rt = 0; rt < 2; ++rt) {
        const unsigned char* qbb = qp + ((size_t)((rowBase >> 4) + rt) << 11) + (size_t)lane * 16;
        lx2 p0 = *reinterpret_cast<const lx2*>(qbb);
        lx2 p1 = *reinterpret_cast<const lx2*>(qbb + 1024);
        qfrag[rt][0] = p0[0]; qfrag[rt][1] = p0[1];
        qfrag[rt][2] = p1[0]; qfrag[rt][3] = p1[1];
    }

    int qidrow[2][4];
    #pragma unroll
    for (int rt = 0; rt < 2; ++rt)
        #pragma unroll
        for (int r = 0; r < 4; ++r)
            qidrow[rt][r] = qids[rowBase + rt * 16 + quad * 4 + r];

    float den[2][4], num[2][4], mxv[2][4], mxp[2][4];
    #pragma unroll
    for (int rt = 0; rt < 2; ++rt)
        #pragma unroll
        for (int r = 0; r < 4; ++r) {
            den[rt][r] = 0.f; num[rt][r] = 0.f;
            mxv[rt][r] = -INFINITY; mxp[rt][r] = -INFINITY;
        }

    const float L2E = 1.4426950408889634f;   // log2(e)
    const float CB  = 64.0f;                 // fixed exponent bias; cancels in num/den

    const int colStart = cs * 1024 + wave * 256;
    const int tileBase = colStart >> 4;

    #pragma unroll 2
    for (int t = 0; t < T_ITERS; ++t) {
        const int c  = colStart + t * 16 + l15;
        const int qc = qids[c];
        const float wc = 1.0f - 0.1f * ranks[c];

        // Packed B-frags: two 1 KB-contiguous b128 loads per iter (fp8: half of bf16).
        const unsigned char* bb = ap + ((size_t)(tileBase + t) << 11) + (size_t)lane * 16;
        lx2 b01 = *reinterpret_cast<const lx2*>(bb);
        lx2 b23 = *reinterpret_cast<const lx2*>(bb + 1024);
        long bfrag[4] = { b01[0], b01[1], b23[0], b23[1] };

        f32x4 acc0 = {0.f, 0.f, 0.f, 0.f};
        f32x4 acc1 = {0.f, 0.f, 0.f, 0.f};
        #pragma unroll
        for (int s = 0; s < 4; ++s) {
            acc0 = __builtin_amdgcn_mfma_f32_16x16x32_fp8_fp8(qfrag[0][s], bfrag[s], acc0, 0, 0, 0);
            acc1 = __builtin_amdgcn_mfma_f32_16x16x32_fp8_fp8(qfrag[1][s], bfrag[s], acc1, 0, 0, 0);
        }

        #pragma unroll
        for (int r = 0; r < 4; ++r) {
            {
                float sv = acc0[r];
                float e  = __builtin_amdgcn_exp2f(fmaf(sv, L2E, -CB));
                bool pos = (qc == qidrow[0][r]);
                den[0][r] += e;
                num[0][r] = fmaf(pos ? wc : 0.0f, e, num[0][r]);
                mxv[0][r] = fmaxf(mxv[0][r], sv);
                mxp[0][r] = fmaxf(mxp[0][r], pos ? sv : -INFINITY);
            }
            {
                float sv = acc1[r];
                float e  = __builtin_amdgcn_exp2f(fmaf(sv, L2E, -CB));
                bool pos = (qc == qidrow[1][r]);
                den[1][r] += e;
                num[1][r] = fmaf(pos ? wc : 0.0f, e, num[1][r]);
                mxv[1][r] = fmaxf(mxv[1][r], sv);
                mxp[1][r] = fmaxf(mxp[1][r], pos ? sv : -INFINITY);
            }
        }
    }

    // Reduce across the 16 lanes of each quad (same rows, different cols).
    #pragma unroll
    for (int m = 1; m <= 8; m <<= 1) {
        #pragma unroll
        for (int rt = 0; rt < 2; ++rt)
            #pragma unroll
            for (int r = 0; r < 4; ++r) {
                den[rt][r] += __shfl_xor(den[rt][r], m, 64);
                num[rt][r] += __shfl_xor(num[rt][r], m, 64);
                mxv[rt][r]  = fmaxf(mxv[rt][r], __shfl_xor(mxv[rt][r], m, 64));
                mxp[rt][r]  = fmaxf(mxp[rt][r], __shfl_xor(mxp[rt][r], m, 64));
            }
    }

    __shared__ float sden[4][32], snum[4][32], smax[4][32], smaxp[4][32];
    if (l15 == 0) {
        #pragma unroll
        for (int rt = 0; rt < 2; ++rt)
            #pragma unroll
            for (int r = 0; r < 4; ++r) {
                int lr = rt * 16 + quad * 4 + r;
                sden[wave][lr]  = den[rt][r];
                snum[wave][lr]  = num[rt][r];
                smax[wave][lr]  = mxv[rt][r];
                smaxp[wave][lr] = mxp[rt][r];
            }
    }
    __syncthreads();

    __shared__ int slast;
    if (tid < 32) {   // wave 0: merge across waves + agent-scope partial stores
        float d = 0.f, n = 0.f, mv = -INFINITY, mp = -INFINITY;
        #pragma unroll
        for (int w = 0; w < 4; ++w) {
            d += sden[w][tid];
            n += snum[w][tid];
            mv = fmaxf(mv, smax[w][tid]);
            mp = fmaxf(mp, smaxp[w][tid]);
        }
        const int row = rowBase + tid;
        __hip_atomic_store(&pden[cs * B_N + row],  d,  __ATOMIC_RELAXED, __HIP_MEMORY_SCOPE_AGENT);
        __hip_atomic_store(&pnum[cs * B_N + row],  n,  __ATOMIC_RELAXED, __HIP_MEMORY_SCOPE_AGENT);
        __hip_atomic_store(&pmax[cs * B_N + row],  mv, __ATOMIC_RELAXED, __HIP_MEMORY_SCOPE_AGENT);
        __hip_atomic_store(&pmaxp[cs * B_N + row], mp, __ATOMIC_RELAXED, __HIP_MEMORY_SCOPE_AGENT);
        if (tid == 0) {
            __builtin_amdgcn_fence(__ATOMIC_RELEASE, "agent");  // order partial stores before cnt
            unsigned old = __hip_atomic_fetch_add(cnt, 1u, __ATOMIC_RELAXED, __HIP_MEMORY_SCOPE_AGENT);
            slast = (old == GRID_MPL - 1) ? 1 : 0;
        }
    }
    __syncthreads();
    if (!slast) return;

    // ---- last-block finalize (replaces the fin dispatch) ----
    __builtin_amdgcn_fence(__ATOMIC_ACQUIRE, "agent");
    float lsum = 0.f, csum = 0.f;
    for (int base = tid * 4; base < B_N; base += 1024) {
        f32x4 d4 = {0.f, 0.f, 0.f, 0.f}, n4 = {0.f, 0.f, 0.f, 0.f};
        f32x4 v4 = {-INFINITY, -INFINITY, -INFINITY, -INFINITY};
        f32x4 p4 = {-INFINITY, -INFINITY, -INFINITY, -INFINITY};
        #pragma unroll
        for (int c2 = 0; c2 < CSPLIT; ++c2) {
            const f32x4 dd = *reinterpret_cast<const f32x4*>(&pden[c2 * B_N + base]);
            const f32x4 nn = *reinterpret_cast<const f32x4*>(&pnum[c2 * B_N + base]);
            const f32x4 vv = *reinterpret_cast<const f32x4*>(&pmax[c2 * B_N + base]);
            const f32x4 pp = *reinterpret_cast<const f32x4*>(&pmaxp[c2 * B_N + base]);
            d4 += dd; n4 += nn;
            #pragma unroll
            for (int j = 0; j < 4; ++j) {
                v4[j] = fmaxf(v4[j], vv[j]);
                p4[j] = fmaxf(p4[j], pp[j]);
            }
        }
        #pragma unroll
        for (int j = 0; j < 4; ++j) {
            lsum += -logf(n4[j] / d4[j] + 1e-8f);
            csum += (p4[j] == v4[j]) ? 1.0f : 0.0f;
        }
    }
    #pragma unroll
    for (int m = 1; m <= 32; m <<= 1) {
        lsum += __shfl_xor(lsum, m, 64);
        csum += __shfl_xor(csum, m, 64);
    }
    __shared__ float sl[4], sc[4];
    if ((tid & 63) == 0) { sl[wave] = lsum; sc[wave] = csum; }
    __syncthreads();
    if (tid == 0) {
        out[0] = (sl[0] + sl[1] + sl[2] + sl[3]) * (1.0f / B_N);
        out[1] = (sc[0] + sc[1] + sc[2] + sc[3]) * (1.0f / B_N);
    }
}

extern "C" void kernel_launch(void* const* d_in, const int* in_sizes, int n_in,
                              void* d_out, int out_size, void* d_ws, size_t ws_size,
                              hipStream_t stream) {
    const float* q     = (const float*)d_in[0];
    const float* a     = (const float*)d_in[1];
    const int*   qids  = (const int*)d_in[2];
    const float* ranks = (const float*)d_in[3];
    float* out = (float*)d_out;

    unsigned char* qp = (unsigned char*)d_ws;                       // 1 MB packed fp8 Q
    unsigned char* ap = qp + (size_t)B_N * D_K;                     // 1 MB packed fp8 A
    char* p = (char*)(ap + (size_t)B_N * D_K);
    float* pden  = (float*)p;                p += CSPLIT * B_N * sizeof(float);
    float* pnum  = (float*)p;                p += CSPLIT * B_N * sizeof(float);
    float* pmax  = (float*)p;                p += CSPLIT * B_N * sizeof(float);
    float* pmaxp = (float*)p;                p += CSPLIT * B_N * sizeof(float);
    unsigned int* cnt = (unsigned int*)p;

    cvt_kernel<<<(B_N * D_K / 8) / 256, 256, 0, stream>>>(q, a, qp, ap, cnt);
    mpl_kernel<<<GRID_MPL, 256, 0, stream>>>(qp, ap, qids, ranks,
                                             pden, pnum, pmax, pmaxp, cnt, out);
}

// Round 8
// 109.261 us; speedup vs baseline: 1.2012x; 1.2012x over previous
//
#include <hip/hip_runtime.h>
#include <hip/hip_bf16.h>
#include <cmath>

#define B_N 8192
#define D_K 128
#define ROWS 64            // rows per block (R8: 2x work/wave, halves B traffic per value)
#define CSPLIT 8           // column splits; block covers 1024 cols
#define T_ITERS 16         // 16-col tiles per wave: 1024 / 4 waves / 16

typedef short bf16x8 __attribute__((ext_vector_type(8)));
typedef unsigned short u16x8 __attribute__((ext_vector_type(8)));
typedef float f32x4  __attribute__((ext_vector_type(4)));

__device__ inline unsigned short f2bf(float f) {
    unsigned u = __builtin_bit_cast(unsigned, f);
    u += 0x7fffu + ((u >> 16) & 1u);   // round-to-nearest-even
    return (unsigned short)(u >> 16);
}

// Convert fp32 Q (row-major bf16) and A (MFMA-fragment-packed bf16).
// A packed layout (R4-verified win): per 16-col tile T, k-step s (32 k), 1 KB
// region at (T*4+s)*1024 B; lane L holds 16 B at L*16 covering
// A[col=T*16+(L&15)][k = s*32 + (L>>4)*8 .. +7].
// Also zeroes d_out (harness re-poisons it to 0xAA before every replay).
__global__ void cvt_kernel(const float* __restrict__ q, const float* __restrict__ a,
                           unsigned short* __restrict__ qb, unsigned short* __restrict__ ab,
                           float* __restrict__ out) {
    int g = blockIdx.x * blockDim.x + threadIdx.x;   // 0 .. B*D/8-1
    if (g < 2) out[g] = 0.0f;
    float4 q0 = reinterpret_cast<const float4*>(q)[g * 2];
    float4 q1 = reinterpret_cast<const float4*>(q)[g * 2 + 1];
    u16x8 oq;
    oq[0] = f2bf(q0.x); oq[1] = f2bf(q0.y); oq[2] = f2bf(q0.z); oq[3] = f2bf(q0.w);
    oq[4] = f2bf(q1.x); oq[5] = f2bf(q1.y); oq[6] = f2bf(q1.z); oq[7] = f2bf(q1.w);
    *reinterpret_cast<u16x8*>(qb + (size_t)g * 8) = oq;

    float4 a0 = reinterpret_cast<const float4*>(a)[g * 2];
    float4 a1 = reinterpret_cast<const float4*>(a)[g * 2 + 1];
    u16x8 oa;
    oa[0] = f2bf(a0.x); oa[1] = f2bf(a0.y); oa[2] = f2bf(a0.z); oa[3] = f2bf(a0.w);
    oa[4] = f2bf(a1.x); oa[5] = f2bf(a1.y); oa[6] = f2bf(a1.z); oa[7] = f2bf(a1.w);
    const int col = g >> 4, sq = g & 15, s = sq >> 2, quad = sq & 3;
    const int chunk = ((col >> 4) * 4 + s) * 64 + quad * 16 + (col & 15);
    *reinterpret_cast<u16x8*>(ab + (size_t)chunk * 8) = oa;
}

// Partial kernel: block (rg, cs) computes rows [rg*64,+64) over cols [cs*1024,+1024).
// 256 threads = 4 waves; wave owns 256 cols (16 tiles). Four 16-row tiles per wave.
// MFMA 16x16x32 bf16 (m89-verified layouts):
//   A-op: lane holds A[m=lane&15][k=(lane>>4)*8+j]; B-op transposed same;
//   C/D : col=lane&15, row=(lane>>4)*4+reg.
// qids/ranks for the wave's 256 cols preloaded to 8 VGPRs, extracted per-iter by
// __shfl (removes 2 global loads/iter from the critical path).
// VGPR ~200 -> __launch_bounds__(256,2): cap 256, NO spills (R2 sentinel: WRITE_SIZE).
__launch_bounds__(256, 2)
__global__ void mpl_part_kernel(const unsigned short* __restrict__ qb,
                                const unsigned short* __restrict__ ab,
                                const int* __restrict__ qids,
                                const float* __restrict__ ranks,
                                float* __restrict__ pden, float* __restrict__ pnum,
                                float* __restrict__ pmax, float* __restrict__ pmaxp) {
    const int tid  = threadIdx.x;
    const int lane = tid & 63;
    const int wave = tid >> 6;               // 0..3
    const int rg   = blockIdx.x >> 3;        // 0..127
    const int cs   = blockIdx.x & 7;         // 0..7 (== XCD id under %8 dispatch)
    const int rowBase = rg * ROWS;
    const int quad = lane >> 4;              // 0..3
    const int l15  = lane & 15;

    // Q fragments: 4 row-tiles x 4 k-steps (64 VGPRs).
    bf16x8 qfrag[4][4];
    #pragma unroll
    for (int rt = 0; rt < 4; ++rt) {
        const unsigned short* qrow = qb + (size_t)(rowBase + rt * 16 + l15) * D_K + quad * 8;
        #pragma unroll
        for (int s = 0; s < 4; ++s)
            qfrag[rt][s] = *reinterpret_cast<const bf16x8*>(qrow + s * 32);
    }

    int qidrow[4][4];
    #pragma unroll
    for (int rt = 0; rt < 4; ++rt)
        #pragma unroll
        for (int r = 0; r < 4; ++r)
            qidrow[rt][r] = qids[rowBase + rt * 16 + quad * 4 + r];

    const int colStart = cs * 1024 + wave * 256;
    // Preload this wave's 256 col qids/ranks into registers (4+4 VGPRs).
    int   qreg[4];
    float rreg[4];
    #pragma unroll
    for (int j = 0; j < 4; ++j) {
        qreg[j] = qids[colStart + j * 64 + lane];
        rreg[j] = ranks[colStart + j * 64 + lane];
    }

    float den[4][4], num[4][4], mxv[4][4], mxp[4][4];
    #pragma unroll
    for (int rt = 0; rt < 4; ++rt)
        #pragma unroll
        for (int r = 0; r < 4; ++r) {
            den[rt][r] = 0.f; num[rt][r] = 0.f;
            mxv[rt][r] = -INFINITY; mxp[rt][r] = -INFINITY;
        }

    const float L2E = 1.4426950408889634f;   // log2(e)
    const float CB  = 64.0f;                 // fixed exponent bias; cancels in num/den
    const int tileBase = colStart >> 4;

    #pragma unroll 2
    for (int t = 0; t < T_ITERS; ++t) {
        // per-iter scalars from preloaded regs (no global access)
        const int   src = (t & 3) * 16 + l15;
        const int   qc  = __shfl(qreg[t >> 2], src, 64);
        const float wc  = 1.0f - 0.1f * __shfl(rreg[t >> 2], src, 64);

        // Packed B-frag: 1 KB contiguous per b128 (lane*16B), 4 per tile.
        const unsigned short* bbase = ab + ((size_t)(tileBase + t) * 4) * 512 + lane * 8;
        bf16x8 bfrag[4];
        #pragma unroll
        for (int s = 0; s < 4; ++s)
            bfrag[s] = *reinterpret_cast<const bf16x8*>(bbase + s * 512);

        f32x4 acc[4];
        #pragma unroll
        for (int rt = 0; rt < 4; ++rt) acc[rt] = f32x4{0.f, 0.f, 0.f, 0.f};
        #pragma unroll
        for (int s = 0; s < 4; ++s)
            #pragma unroll
            for (int rt = 0; rt < 4; ++rt)   // 4 independent MFMA chains
                acc[rt] = __builtin_amdgcn_mfma_f32_16x16x32_bf16(qfrag[rt][s], bfrag[s], acc[rt], 0, 0, 0);

        #pragma unroll
        for (int rt = 0; rt < 4; ++rt)
            #pragma unroll
            for (int r = 0; r < 4; ++r) {
                float sv = acc[rt][r];
                float e  = __builtin_amdgcn_exp2f(fmaf(sv, L2E, -CB));
                bool pos = (qc == qidrow[rt][r]);
                den[rt][r] += e;
                num[rt][r] = fmaf(pos ? wc : 0.0f, e, num[rt][r]);
                mxv[rt][r] = fmaxf(mxv[rt][r], sv);
                mxp[rt][r] = fmaxf(mxp[rt][r], pos ? sv : -INFINITY);
            }
    }

    // Reduce across the 16 lanes of each quad (same rows, different cols).
    #pragma unroll
    for (int m = 1; m <= 8; m <<= 1) {
        #pragma unroll
        for (int rt = 0; rt < 4; ++rt)
            #pragma unroll
            for (int r = 0; r < 4; ++r) {
                den[rt][r] += __shfl_xor(den[rt][r], m, 64);
                num[rt][r] += __shfl_xor(num[rt][r], m, 64);
                mxv[rt][r]  = fmaxf(mxv[rt][r], __shfl_xor(mxv[rt][r], m, 64));
                mxp[rt][r]  = fmaxf(mxp[rt][r], __shfl_xor(mxp[rt][r], m, 64));
            }
    }

    __shared__ float sden[4][ROWS], snum[4][ROWS], smax[4][ROWS], smaxp[4][ROWS];
    if (l15 == 0) {
        #pragma unroll
        for (int rt = 0; rt < 4; ++rt)
            #pragma unroll
            for (int r = 0; r < 4; ++r) {
                int lr = rt * 16 + quad * 4 + r;
                sden[wave][lr]  = den[rt][r];
                snum[wave][lr]  = num[rt][r];
                smax[wave][lr]  = mxv[rt][r];
                smaxp[wave][lr] = mxp[rt][r];
            }
    }
    __syncthreads();

    if (tid < ROWS) {
        int lr = tid;
        float d = 0.f, n = 0.f, mv = -INFINITY, mp = -INFINITY;
        #pragma unroll
        for (int w = 0; w < 4; ++w) {
            d += sden[w][lr];
            n += snum[w][lr];
            mv = fmaxf(mv, smax[w][lr]);
            mp = fmaxf(mp, smaxp[w][lr]);
        }
        const int row = rowBase + lr;
        pden[cs * B_N + row]  = d;
        pnum[cs * B_N + row]  = n;
        pmax[cs * B_N + row]  = mv;
        pmaxp[cs * B_N + row] = mp;
    }
}

// Finalize: 32 blocks x 256 threads, one row per thread (coalesced partial reads),
// block-reduce, atomicAdd into d_out (zeroed by cvt_kernel).
__launch_bounds__(256, 4)
__global__ void fin_kernel(const float* __restrict__ pden, const float* __restrict__ pnum,
                           const float* __restrict__ pmax, const float* __restrict__ pmaxp,
                           float* __restrict__ out) {
    const int r = blockIdx.x * 256 + threadIdx.x;
    float d = 0.f, n = 0.f, mv = -INFINITY, mp = -INFINITY;
    #pragma unroll
    for (int cs = 0; cs < CSPLIT; ++cs) {
        d += pden[cs * B_N + r];
        n += pnum[cs * B_N + r];
        mv = fmaxf(mv, pmax[cs * B_N + r]);
        mp = fmaxf(mp, pmaxp[cs * B_N + r]);
    }
    float lsum = -logf(n / d + 1e-8f);
    float csum = (mp == mv) ? 1.0f : 0.0f;   // argmax col positive <=> pos-max == global max
    #pragma unroll
    for (int m = 1; m <= 32; m <<= 1) {
        lsum += __shfl_xor(lsum, m, 64);
        csum += __shfl_xor(csum, m, 64);
    }
    __shared__ float sl[4], sc[4];
    const int wave = threadIdx.x >> 6;
    if ((threadIdx.x & 63) == 0) { sl[wave] = lsum; sc[wave] = csum; }
    __syncthreads();
    if (threadIdx.x == 0) {
        float L = sl[0] + sl[1] + sl[2] + sl[3];
        float C = sc[0] + sc[1] + sc[2] + sc[3];
        atomicAdd(&out[0], L * (1.0f / B_N));
        atomicAdd(&out[1], C * (1.0f / B_N));
    }
}

extern "C" void kernel_launch(void* const* d_in, const int* in_sizes, int n_in,
                              void* d_out, int out_size, void* d_ws, size_t ws_size,
                              hipStream_t stream) {
    const float* q     = (const float*)d_in[0];
    const float* a     = (const float*)d_in[1];
    const int*   qids  = (const int*)d_in[2];
    const float* ranks = (const float*)d_in[3];
    float* out = (float*)d_out;

    unsigned short* qb = (unsigned short*)d_ws;
    unsigned short* ab = qb + (size_t)B_N * D_K;
    char* p = (char*)(ab + (size_t)B_N * D_K);
    float* pden  = (float*)p;                p += CSPLIT * B_N * sizeof(float);
    float* pnum  = (float*)p;                p += CSPLIT * B_N * sizeof(float);
    float* pmax  = (float*)p;                p += CSPLIT * B_N * sizeof(float);
    float* pmaxp = (float*)p;

    cvt_kernel<<<(B_N * D_K / 8) / 256, 256, 0, stream>>>(q, a, qb, ab, out);
    mpl_part_kernel<<<(B_N / ROWS) * CSPLIT, 256, 0, stream>>>(qb, ab, qids, ranks,
                                                               pden, pnum, pmax, pmaxp);
    fin_kernel<<<B_N / 256, 256, 0, stream>>>(pden, pnum, pmax, pmaxp, out);
}

// Round 9
// 99.820 us; speedup vs baseline: 1.3148x; 1.0946x over previous
//
#include <hip/hip_runtime.h>
#include <hip/hip_bf16.h>
#include <cmath>

#define B_N 8192
#define D_K 128
#define ROWS 64            // rows per block; wave w owns rows [w*16, +16)
#define CSPLIT 8           // column splits; block covers 1024 cols
#define T_OUT 16           // 64-col super-tiles per block: 1024/64

typedef short bf16x8 __attribute__((ext_vector_type(8)));
typedef unsigned short u16x8 __attribute__((ext_vector_type(8)));
typedef float f32x4  __attribute__((ext_vector_type(4)));

typedef __attribute__((address_space(3))) unsigned int as3_uint;
typedef __attribute__((address_space(1))) unsigned int as1_uint;

// Async global->LDS DMA, 16 B/lane. HW dest = wave-uniform base + lane*16.
// AS casts via integer round-trip (generic LDS ptr low 32 bits = LDS offset on gfx9).
__device__ __forceinline__ void gl_lds16(const void* g, void* l) {
    __builtin_amdgcn_global_load_lds((const as1_uint*)(uintptr_t)g,
                                     (as3_uint*)(unsigned int)(uintptr_t)l,
                                     16, 0, 0);
}

__device__ inline unsigned short f2bf(float f) {
    unsigned u = __builtin_bit_cast(unsigned, f);
    u += 0x7fffu + ((u >> 16) & 1u);   // round-to-nearest-even
    return (unsigned short)(u >> 16);
}

// Convert fp32 Q (row-major bf16) and A (MFMA-fragment-packed bf16).
// A packed layout (R4-verified win): per 16-col tile T, k-step s (32 k), 1 KB
// region at (T*4+s)*1024 B; lane L holds 16 B at L*16 covering
// A[col=T*16+(L&15)][k = s*32 + (L>>4)*8 .. +7]. 4 consecutive tiles = 16 KB
// contiguous = one LDS super-tile stage. Also zeroes d_out (re-poisoned 0xAA).
__global__ void cvt_kernel(const float* __restrict__ q, const float* __restrict__ a,
                           unsigned short* __restrict__ qb, unsigned short* __restrict__ ab,
                           float* __restrict__ out) {
    int g = blockIdx.x * blockDim.x + threadIdx.x;   // 0 .. B*D/8-1
    if (g < 2) out[g] = 0.0f;
    float4 q0 = reinterpret_cast<const float4*>(q)[g * 2];
    float4 q1 = reinterpret_cast<const float4*>(q)[g * 2 + 1];
    u16x8 oq;
    oq[0] = f2bf(q0.x); oq[1] = f2bf(q0.y); oq[2] = f2bf(q0.z); oq[3] = f2bf(q0.w);
    oq[4] = f2bf(q1.x); oq[5] = f2bf(q1.y); oq[6] = f2bf(q1.z); oq[7] = f2bf(q1.w);
    *reinterpret_cast<u16x8*>(qb + (size_t)g * 8) = oq;

    float4 a0 = reinterpret_cast<const float4*>(a)[g * 2];
    float4 a1 = reinterpret_cast<const float4*>(a)[g * 2 + 1];
    u16x8 oa;
    oa[0] = f2bf(a0.x); oa[1] = f2bf(a0.y); oa[2] = f2bf(a0.z); oa[3] = f2bf(a0.w);
    oa[4] = f2bf(a1.x); oa[5] = f2bf(a1.y); oa[6] = f2bf(a1.z); oa[7] = f2bf(a1.w);
    const int col = g >> 4, sq = g & 15, s = sq >> 2, quad = sq & 3;
    const int chunk = ((col >> 4) * 4 + s) * 64 + quad * 16 + (col & 15);
    *reinterpret_cast<u16x8*>(ab + (size_t)chunk * 8) = oa;
}

// Block (rg, cs): rows [rg*64,+64) over cols [cs*1024,+1024). 4 waves; wave w owns
// rows [rg*64 + w*16, +16); all waves sweep the same cols via LDS-shared B-tiles.
// Double-buffered LDS (2 x 16 KB); stage t+1 issued AFTER the barrier publishing t
// (m97 structure: the drain at the next barrier is cheap — a full compute phase of
// slack). ds_read_b128 at lane*16: conflict-free.
// MFMA 16x16x32 bf16 (m89-verified layouts):
//   A-op: lane holds A[m=lane&15][k=(lane>>4)*8+j]; B-op transposed same;
//   C/D : col=lane&15, row=(lane>>4)*4+reg.
// No cross-wave stats merge (waves own disjoint rows) -> no LDS reduction arrays.
__launch_bounds__(256, 4)
__global__ void mpl_part_kernel(const unsigned short* __restrict__ qb,
                                const unsigned short* __restrict__ ab,
                                const int* __restrict__ qids,
                                const float* __restrict__ ranks,
                                float* __restrict__ pden, float* __restrict__ pnum,
                                float* __restrict__ pmax, float* __restrict__ pmaxp) {
    __shared__ unsigned short smem[2 * 8192];   // 2 x 16 KB

    const int tid  = threadIdx.x;
    const int lane = tid & 63;
    const int wave = tid >> 6;               // 0..3
    const int rg   = blockIdx.x >> 3;        // 0..127
    const int cs   = blockIdx.x & 7;         // 0..7 (== XCD id under %8 dispatch)
    const int rowBase = rg * ROWS;
    const int quad = lane >> 4;              // 0..3
    const int l15  = lane & 15;

    // Q fragments: this wave's 16-row tile x 4 k-steps (16 VGPRs).
    bf16x8 qfrag[4];
    {
        const unsigned short* qrow = qb + (size_t)(rowBase + wave * 16 + l15) * D_K + quad * 8;
        #pragma unroll
        for (int s = 0; s < 4; ++s)
            qfrag[s] = *reinterpret_cast<const bf16x8*>(qrow + s * 32);
    }

    int qidrow[4];
    #pragma unroll
    for (int r = 0; r < 4; ++r)
        qidrow[r] = qids[rowBase + wave * 16 + quad * 4 + r];

    float den[4], num[4], mxv[4], mxp[4];
    #pragma unroll
    for (int r = 0; r < 4; ++r) {
        den[r] = 0.f; num[r] = 0.f; mxv[r] = -INFINITY; mxp[r] = -INFINITY;
    }

    const float L2E = 1.4426950408889634f;   // log2(e)
    const float CB  = 64.0f;                 // fixed exponent bias; cancels in num/den
    const int colStart = cs * 1024;

    // Packed A bytes for this block's col strip: super-tile t at +t*16 KB.
    const char* gstrip = (const char*)ab + (size_t)cs * 64 * 4096;
    const int   chunk  = (wave * 4) * 1024;  // this wave's 4 KB of each 16 KB stage

    // Prologue: stage super-tile 0 into buffer 0.
    #pragma unroll
    for (int r = 0; r < 4; ++r)
        gl_lds16(gstrip + chunk + r * 1024 + lane * 16,
                 (char*)smem + chunk + r * 1024);
    __syncthreads();

    for (int t = 0; t < T_OUT; ++t) {
        const int cur = t & 1, nxt = cur ^ 1;
        // Stage t+1 (async; completes during this iteration's compute).
        if (t + 1 < T_OUT) {
            const char* gsrc = gstrip + (size_t)(t + 1) * 16384 + chunk;
            char*       ldst = (char*)smem + nxt * 16384 + chunk;
            #pragma unroll
            for (int r = 0; r < 4; ++r)
                gl_lds16(gsrc + r * 1024 + lane * 16, ldst + r * 1024);
        }

        // Compute from buffer cur: 4 sub-tiles x 4 k-steps.
        const unsigned short* lbase = smem + cur * 8192 + lane * 8;
        f32x4 acc[4];
        #pragma unroll
        for (int u = 0; u < 4; ++u) acc[u] = f32x4{0.f, 0.f, 0.f, 0.f};
        #pragma unroll
        for (int u = 0; u < 4; ++u)
            #pragma unroll
            for (int s = 0; s < 4; ++s) {
                bf16x8 bfrag = *reinterpret_cast<const bf16x8*>(lbase + u * 2048 + s * 512);
                acc[u] = __builtin_amdgcn_mfma_f32_16x16x32_bf16(qfrag[s], bfrag, acc[u], 0, 0, 0);
            }

        #pragma unroll
        for (int u = 0; u < 4; ++u) {
            const int c  = colStart + t * 64 + u * 16 + l15;
            const int qc = qids[c];
            const float wc = 1.0f - 0.1f * ranks[c];
            #pragma unroll
            for (int r = 0; r < 4; ++r) {
                float sv = acc[u][r];
                float e  = __builtin_amdgcn_exp2f(fmaf(sv, L2E, -CB));
                bool pos = (qc == qidrow[r]);
                den[r] += e;
                num[r] = fmaf(pos ? wc : 0.0f, e, num[r]);
                mxv[r] = fmaxf(mxv[r], sv);
                mxp[r] = fmaxf(mxp[r], pos ? sv : -INFINITY);
            }
        }
        __syncthreads();   // reads of cur done (lgkm drain) + stage of nxt done (vm drain)
    }

    // Reduce across the 16 lanes of each quad (same rows, different cols).
    #pragma unroll
    for (int m = 1; m <= 8; m <<= 1) {
        #pragma unroll
        for (int r = 0; r < 4; ++r) {
            den[r] += __shfl_xor(den[r], m, 64);
            num[r] += __shfl_xor(num[r], m, 64);
            mxv[r]  = fmaxf(mxv[r], __shfl_xor(mxv[r], m, 64));
            mxp[r]  = fmaxf(mxp[r], __shfl_xor(mxp[r], m, 64));
        }
    }

    if (l15 == 0) {   // lanes 0,16,32,48: write 4 rows each (wave-exclusive rows)
        const int rb = cs * B_N + rowBase + wave * 16 + quad * 4;
        #pragma unroll
        for (int r = 0; r < 4; ++r) {
            pden[rb + r]  = den[r];
            pnum[rb + r]  = num[r];
            pmax[rb + r]  = mxv[r];
            pmaxp[rb + r] = mxp[r];
        }
    }
}

// Finalize: 32 blocks x 256 threads, one row per thread (coalesced partial reads),
// block-reduce, atomicAdd into d_out (zeroed by cvt_kernel).
__launch_bounds__(256, 4)
__global__ void fin_kernel(const float* __restrict__ pden, const float* __restrict__ pnum,
                           const float* __restrict__ pmax, const float* __restrict__ pmaxp,
                           float* __restrict__ out) {
    const int r = blockIdx.x * 256 + threadIdx.x;
    float d = 0.f, n = 0.f, mv = -INFINITY, mp = -INFINITY;
    #pragma unroll
    for (int cs = 0; cs < CSPLIT; ++cs) {
        d += pden[cs * B_N + r];
        n += pnum[cs * B_N + r];
        mv = fmaxf(mv, pmax[cs * B_N + r]);
        mp = fmaxf(mp, pmaxp[cs * B_N + r]);
    }
    float lsum = -logf(n / d + 1e-8f);
    float csum = (mp == mv) ? 1.0f : 0.0f;   // argmax col positive <=> pos-max == global max
    #pragma unroll
    for (int m = 1; m <= 32; m <<= 1) {
        lsum += __shfl_xor(lsum, m, 64);
        csum += __shfl_xor(csum, m, 64);
    }
    __shared__ float sl[4], sc[4];
    const int wave = threadIdx.x >> 6;
    if ((threadIdx.x & 63) == 0) { sl[wave] = lsum; sc[wave] = csum; }
    __syncthreads();
    if (threadIdx.x == 0) {
        float L = sl[0] + sl[1] + sl[2] + sl[3];
        float C = sc[0] + sc[1] + sc[2] + sc[3];
        atomicAdd(&out[0], L * (1.0f / B_N));
        atomicAdd(&out[1], C * (1.0f / B_N));
    }
}

extern "C" void kernel_launch(void* const* d_in, const int* in_sizes, int n_in,
                              void* d_out, int out_size, void* d_ws, size_t ws_size,
                              hipStream_t stream) {
    const float* q     = (const float*)d_in[0];
    const float* a     = (const float*)d_in[1];
    const int*   qids  = (const int*)d_in[2];
    const float* ranks = (const float*)d_in[3];
    float* out = (float*)d_out;

    unsigned short* qb = (unsigned short*)d_ws;
    unsigned short* ab = qb + (size_t)B_N * D_K;
    char* p = (char*)(ab + (size_t)B_N * D_K);
    float* pden  = (float*)p;                p += CSPLIT * B_N * sizeof(float);
    float* pnum  = (float*)p;                p += CSPLIT * B_N * sizeof(float);
    float* pmax  = (float*)p;                p += CSPLIT * B_N * sizeof(float);
    float* pmaxp = (float*)p;

    cvt_kernel<<<(B_N * D_K / 8) / 256, 256, 0, stream>>>(q, a, qb, ab, out);
    mpl_part_kernel<<<(B_N / ROWS) * CSPLIT, 256, 0, stream>>>(qb, ab, qids, ranks,
                                                               pden, pnum, pmax, pmaxp);
    fin_kernel<<<B_N / 256, 256, 0, stream>>>(pden, pnum, pmax, pmaxp, out);
}